// Round 12
// baseline (1270.433 us; speedup 1.0000x reference)
//
#include <hip/hip_runtime.h>

#define NN 100000
#define NGRAPH 64
#define NPART 8
#define NPB 12500
#define DB 16
#define WSL 192
#define AVGLOG 3.4965075614664802f

using f32x4 = __attribute__((ext_vector_type(4))) float;
using f16x8 = __attribute__((ext_vector_type(8))) _Float16;
using f16x4 = __attribute__((ext_vector_type(4))) _Float16;

// ---------------- CSR build ----------------
// Pass 1: wave-private LDS binning, barrier-free. Cursor = wave-uniform
// register; append = ballot+rank store; flush (>=128) = 1 global atomic by
// lane0 + 2 coalesced stores/lane. No __syncthreads in hot loop -> loads
// pipeline across chunks.
__global__ __launch_bounds__(256) void k_binstage(
    const int* __restrict__ ei, int* __restrict__ bcur,
    unsigned long long* __restrict__ bkt, int cap, int E) {
  __shared__ unsigned long long s_b[4][NPART][WSL];
  const int tid = threadIdx.x, w = tid >> 6, lane = tid & 63;
  int cur[NPART];
#pragma unroll
  for (int b = 0; b < NPART; ++b) cur[b] = 0;
  const int nw = gridDim.x * 4;
  const int gw = blockIdx.x * 4 + w;
  const int nch = (E + 63) >> 6;
  for (int ch = gw; ch < nch; ch += nw) {
    int e = ch * 64 + lane;
    int b = -1;
    unsigned long long v = 0;
    if (e < E) {
      int d = __builtin_nontemporal_load(&ei[E + e]);
      int s = __builtin_nontemporal_load(&ei[e]);
      b = d / NPB;
      v = ((unsigned long long)(unsigned)d << 32) | (unsigned)s;
    }
#pragma unroll
    for (int b0 = 0; b0 < NPART; ++b0) {
      unsigned long long mask = __ballot(b == b0);
      if (mask) {  // wave-uniform
        int cnt = __popcll(mask);
        int base = cur[b0];
        if (b == b0) {
          int off = __popcll(mask & ((1ull << lane) - 1ull));
          s_b[w][b0][base + off] = v;
        }
        cur[b0] = base + cnt;          // <= 127+64 = 191 <= WSL
        if (cur[b0] >= 128) {          // wave-uniform flush
          int gbase = 0;
          if (lane == 0) gbase = atomicAdd(&bcur[b0], 128);
          gbase = __shfl(gbase, 0);
#pragma unroll
          for (int k = 0; k < 2; ++k)
            bkt[(size_t)b0 * cap + gbase + k * 64 + lane] = s_b[w][b0][k * 64 + lane];
          int rem = cur[b0] - 128;     // <= 63, reads [128..191) -> no overlap
          if (lane < rem) s_b[w][b0][lane] = s_b[w][b0][128 + lane];
          cur[b0] = rem;
        }
      }
    }
  }
#pragma unroll
  for (int b0 = 0; b0 < NPART; ++b0) {
    int c = cur[b0];
    if (c) {
      int gbase = 0;
      if (lane == 0) gbase = atomicAdd(&bcur[b0], c);
      gbase = __shfl(gbase, 0);
      for (int k = lane; k < c; k += 64)
        bkt[(size_t)b0 * cap + gbase + k] = s_b[w][b0][k];
    }
  }
}

// Degree histogram per (partition, slice): LDS hist, coalesced slice write.
// Normal loads (no nt) so the chunk primes this XCD's L2 for k_binfill.
__global__ __launch_bounds__(256) void k_dhist(
    const unsigned long long* __restrict__ bkt, const int* __restrict__ bcur,
    int cap, int* __restrict__ dhist) {
  __shared__ int hist[NPB];
  const int p = blockIdx.x & (NPART - 1);
  const int b = blockIdx.x >> 3;
  const int tid = threadIdx.x;
  for (int i = tid; i < NPB; i += 256) hist[i] = 0;
  __syncthreads();
  const int n = bcur[p];
  const int chunk = (n + DB - 1) / DB;
  const int lo = b * chunk, hi = min(n, lo + chunk);
  const unsigned long long* base = bkt + (size_t)p * cap;
  const int plo = p * NPB;
  for (int i = lo + tid; i < hi; i += 256) {
    unsigned long long v = base[i];
    atomicAdd(&hist[(int)(v >> 32) - plo], 1);
  }
  __syncthreads();
  int* dst = dhist + ((size_t)p * DB + b) * NPB;
  for (int i = tid; i < NPB; i += 256) dst[i] = hist[i];
}

// In-place exclusive slice-scan of dhist; cnt[i] = total; block sums for scan.
__global__ void k_mergesum(int* __restrict__ dhist, int* __restrict__ cnt,
                           int* __restrict__ bsum, int n) {
  __shared__ int s[256];
  int i = blockIdx.x * 256 + threadIdx.x;
  int acc = 0;
  if (i < n) {
    int p = i / NPB, li = i - p * NPB;
    int* hb = dhist + (size_t)p * DB * NPB + li;
#pragma unroll
    for (int b = 0; b < DB; ++b) {
      int t = hb[b * NPB];
      hb[b * NPB] = acc;
      acc += t;
    }
    cnt[i] = acc;
  }
  s[threadIdx.x] = acc;
  __syncthreads();
  for (int off = 128; off > 0; off >>= 1) {
    if (threadIdx.x < off) s[threadIdx.x] += s[threadIdx.x + off];
    __syncthreads();
  }
  if (threadIdx.x == 0) bsum[blockIdx.x] = s[0];
}

// Pass 2: ZERO global atomics. rank[li] preloaded = row_ptr + slice offset;
// per edge one LDS atomic gives the exact final colv position.
__global__ __launch_bounds__(256) void k_binfill(
    const unsigned long long* __restrict__ bkt, const int* __restrict__ bcur,
    int cap, const int* __restrict__ dhist, const int* __restrict__ row_ptr,
    int* __restrict__ colv) {
  __shared__ int rank[NPB];
  const int p = blockIdx.x & (NPART - 1);
  const int b = blockIdx.x >> 3;
  const int tid = threadIdx.x;
  const int plo = p * NPB;
  const int* soff = dhist + ((size_t)p * DB + b) * NPB;
  for (int li = tid; li < NPB; li += 256) rank[li] = row_ptr[plo + li] + soff[li];
  __syncthreads();
  const int n = bcur[p];
  const int chunk = (n + DB - 1) / DB;
  const int lo = b * chunk, hi = min(n, lo + chunk);
  const unsigned long long* base = bkt + (size_t)p * cap;
  for (int i = lo + tid; i < hi; i += 256) {
    unsigned long long v = base[i];
    int d = (int)(v >> 32);
    int s = (int)(v & 0xffffffffu);
    int pos = atomicAdd(&rank[d - plo], 1);
    colv[pos] = s;
  }
}

__global__ void k_scanb(const int* __restrict__ bsum, int* __restrict__ boff, int nb) {
  __shared__ int s[512];
  int t = threadIdx.x;
  int v = (t < nb) ? bsum[t] : 0;
  s[t] = v;
  __syncthreads();
  for (int off = 1; off < 512; off <<= 1) {
    int u = (t >= off) ? s[t - off] : 0;
    __syncthreads();
    s[t] += u;
    __syncthreads();
  }
  if (t < nb) boff[t] = s[t] - v;  // exclusive block offsets
}

__global__ void k_scatter(const int* __restrict__ cnt, const int* __restrict__ boff,
                          int* __restrict__ row_ptr, int n, int etot) {
  __shared__ int s[256];
  int i = blockIdx.x * 256 + threadIdx.x;
  int v = (i < n) ? cnt[i] : 0;
  s[threadIdx.x] = v;
  __syncthreads();
  for (int off = 1; off < 256; off <<= 1) {
    int u = (threadIdx.x >= off) ? s[threadIdx.x - off] : 0;
    __syncthreads();
    s[threadIdx.x] += u;
    __syncthreads();
  }
  if (i < n) row_ptr[i] = boff[blockIdx.x] + s[threadIdx.x] - v;
  if (i == 0) row_ptr[n] = etot;
}

__global__ void k_nodesc(const int* __restrict__ cnt, float* __restrict__ invd,
                         float* __restrict__ s1v, float* __restrict__ s2v, int n) {
  int i = blockIdx.x * 256 + threadIdx.x;
  if (i >= n) return;
  float degc = fmaxf((float)cnt[i], 1.f);
  invd[i] = 1.f / degc;
  float ld = logf(degc + 1.f);
  s1v[i] = ld * (1.f / AVGLOG);
  s2v[i] = AVGLOG / ld;
}

// W [K][FO] fp32 -> fp16 in MFMA B-fragment order
__global__ void k_wtprep(const float* __restrict__ W, _Float16* __restrict__ Wt,
                         int K, int FO, int FOP) {
  int i = blockIdx.x * 256 + threadIdx.x;
  if (i >= FOP * K) return;
  int nn = i / K, k = i - nn * K;
  float v = (nn < FO) ? W[k * FO + nn] : 0.f;
  int NT = FOP >> 4;
  int kt = k >> 5, q = (k >> 3) & 3, j = k & 7;
  int nt = nn >> 4, m = nn & 15;
  size_t idx = (((size_t)kt * NT + nt) * 64 + (q * 16 + m)) * 8 + j;
  Wt[idx] = (_Float16)v;
}

__global__ void k_xconv(const float* __restrict__ x, _Float16* __restrict__ x16, int n) {
  int i = blockIdx.x * 256 + threadIdx.x;
  if (i < n) x16[i] = (_Float16)x[i];
}

// ---------------- Phase A: gather/reduce; writes agg in MFMA A-frag order ----------------
template <int F, int WPE>
__launch_bounds__(256, WPE)
__global__ void k_agg(const _Float16* __restrict__ hin, const int* __restrict__ row_ptr,
                      const int* __restrict__ colv, const float* __restrict__ invd,
                      _Float16* __restrict__ agg) {
  const int tid = threadIdx.x;
  const int r = tid >> 3, g = tid & 7;
  const int n = blockIdx.x * 32 + r;
  const int e0 = row_ptr[n], e1 = row_ptr[n + 1];
  constexpr int SEG = F / 8;
  constexpr int SEG4 = SEG / 4;
  constexpr int KTA = F / 8;
  float sm[SEG], sq[SEG], mn[SEG], mx[SEG];
  const float FINF = __builtin_inff();
#pragma unroll
  for (int j = 0; j < SEG; ++j) { sm[j] = 0.f; sq[j] = 0.f; mn[j] = FINF; mx[j] = -FINF; }
  int e = e0;
  for (; e + 1 < e1; e += 2) {
    int sA = colv[e], sB = colv[e + 1];
    const f16x4* ra = (const f16x4*)(hin + (size_t)sA * F + g * SEG);
    const f16x4* rb = (const f16x4*)(hin + (size_t)sB * F + g * SEG);
#pragma unroll
    for (int c = 0; c < SEG4; ++c) {
      f16x4 va = ra[c], vb = rb[c];
#pragma unroll
      for (int l = 0; l < 4; ++l) {
        float av = (float)va[l], bv = (float)vb[l];
        int j = 4 * c + l;
        sm[j] += av + bv;
        sq[j] += av * av + bv * bv;
        mn[j] = fminf(mn[j], fminf(av, bv));
        mx[j] = fmaxf(mx[j], fmaxf(av, bv));
      }
    }
  }
  if (e < e1) {
    int sA = colv[e];
    const f16x4* ra = (const f16x4*)(hin + (size_t)sA * F + g * SEG);
#pragma unroll
    for (int c = 0; c < SEG4; ++c) {
      f16x4 va = ra[c];
#pragma unroll
      for (int l = 0; l < 4; ++l) {
        float av = (float)va[l];
        int j = 4 * c + l;
        sm[j] += av;
        sq[j] += av * av;
        mn[j] = fminf(mn[j], av);
        mx[j] = fmaxf(mx[j], av);
      }
    }
  }
  float iv = invd[n];
  bool has = (e1 > e0);
  const int m = n & 15;
  const size_t tb = (size_t)(n >> 4) * KTA;
#pragma unroll
  for (int c = 0; c < SEG4; ++c) {
    f16x4 vals[4];
#pragma unroll
    for (int l = 0; l < 4; ++l) {
      int j = 4 * c + l;
      float mean = sm[j] * iv;
      float var = sq[j] * iv - mean * mean;
      float sd = sqrtf(fmaxf(var, 0.f) + 1e-5f);
      vals[0][l] = (_Float16)mean;
      vals[1][l] = has ? (_Float16)mn[j] : (_Float16)0.f;
      vals[2][l] = has ? (_Float16)mx[j] : (_Float16)0.f;
      vals[3][l] = (_Float16)sd;
    }
    int f0 = g * SEG + 4 * c;
#pragma unroll
    for (int a = 0; a < 4; ++a) {
      int kk0 = a * F + f0;
      int kt = kk0 >> 5, q = (kk0 >> 3) & 3, j0 = kk0 & 7;
      *(f16x4*)(agg + (tb + kt) * 512 + (q * 16 + m) * 8 + j0) = vals[a];
    }
  }
}

// ---------------- Phase B: global-direct MFMA GEMM + fused BN column stats ----------------
#define MFMA16(a, b, c) __builtin_amdgcn_mfma_f32_16x16x32_f16(a, b, c, 0, 0, 0)

template <int F, int FO, int FOP, bool RELU, bool STATS, typename OT>
__launch_bounds__(256)
__global__ void k_mlp(const _Float16* __restrict__ hin, const _Float16* __restrict__ agg,
                      const float* __restrict__ s1g, const float* __restrict__ s2g,
                      const _Float16* __restrict__ Wt, const float* __restrict__ bias,
                      OT* __restrict__ hout, float* __restrict__ csum,
                      float* __restrict__ csq) {
  constexpr int F32 = F / 32;
  constexpr int KTA = F / 8;
  constexpr int NT = FOP / 16;
  constexpr int PPW = (2 * NT) / 4;
  constexpr int XW = F + 8;
  __shared__ __align__(16) _Float16 s_x[32][XW];
  __shared__ float s_cs[2][FOP];

  const int tid = threadIdx.x;
  const int n0 = blockIdx.x * 32;

  for (int idx = tid; idx < 32 * (F / 8); idx += 256) {
    int r = idx / (F / 8), c = idx % (F / 8);
    *(f16x8*)&s_x[r][8 * c] = *(const f16x8*)&hin[(size_t)(n0 + r) * F + 8 * c];
  }
  if (STATS)
    for (int u = tid; u < 2 * FOP; u += 256) (&s_cs[0][0])[u] = 0.f;
  __syncthreads();

  const int w = tid >> 6, ln = tid & 63;
  const int lm = ln & 15, q = ln >> 4;
  const int mt = w & 1;
  const int arow = mt * 16 + lm;
  f32x4 acc0[PPW], acc1[PPW], acc2[PPW];
#pragma unroll
  for (int i = 0; i < PPW; ++i)
#pragma unroll
    for (int t = 0; t < 4; ++t) { acc0[i][t] = 0.f; acc1[i][t] = 0.f; acc2[i][t] = 0.f; }

#pragma unroll
  for (int kt = 0; kt < F32; ++kt) {
    f16x8 a = *(const f16x8*)&s_x[arow][kt * 32 + 8 * q];
#pragma unroll
    for (int i = 0; i < PPW; ++i) {
      int nt = (w >> 1) + 2 * i;
      f16x8 b = *(const f16x8*)&Wt[(((size_t)kt * NT + nt) * 64 + ln) * 8];
      acc0[i] = MFMA16(a, b, acc0[i]);
    }
  }
  const size_t atb = (size_t)(blockIdx.x * 2 + mt) * KTA;
#pragma unroll
  for (int kt = 0; kt < KTA; ++kt) {
    f16x8 a = *(const f16x8*)&agg[(atb + kt) * 512 + ln * 8];
#pragma unroll
    for (int i = 0; i < PPW; ++i) {
      int nt = (w >> 1) + 2 * i;
      f16x8 b0 = *(const f16x8*)&Wt[(((size_t)(F32 + kt) * NT + nt) * 64 + ln) * 8];
      acc0[i] = MFMA16(a, b0, acc0[i]);
      f16x8 b1 = *(const f16x8*)&Wt[(((size_t)(F32 + KTA + kt) * NT + nt) * 64 + ln) * 8];
      acc1[i] = MFMA16(a, b1, acc1[i]);
      f16x8 b2 = *(const f16x8*)&Wt[(((size_t)(F32 + 2 * KTA + kt) * NT + nt) * 64 + ln) * 8];
      acc2[i] = MFMA16(a, b2, acc2[i]);
    }
  }

  float s1r[4], s2r[4];
#pragma unroll
  for (int t = 0; t < 4; ++t) {
    int node = n0 + mt * 16 + q * 4 + t;
    s1r[t] = s1g[node];
    s2r[t] = s2g[node];
  }
#pragma unroll
  for (int i = 0; i < PPW; ++i) {
    int nt = (w >> 1) + 2 * i;
    int ncol = nt * 16 + lm;
    if (FOP == FO || ncol < FO) {
      float bs = bias[ncol];
      float cs = 0.f, cq = 0.f;
#pragma unroll
      for (int t = 0; t < 4; ++t) {
        int node = n0 + mt * 16 + q * 4 + t;
        float v = acc0[i][t] + s1r[t] * acc1[i][t] + s2r[t] * acc2[i][t] + bs;
        if (RELU) v = fmaxf(v, 0.f);
        hout[(size_t)node * FO + ncol] = (OT)v;
        cs += v;
        cq += v * v;
      }
      if (STATS) {
        atomicAdd(&s_cs[0][ncol], cs);
        atomicAdd(&s_cs[1][ncol], cq);
      }
    }
  }
  if (STATS) {
    __syncthreads();
    if (tid < FO) {
      atomicAdd(&csum[tid], s_cs[0][tid]);
      atomicAdd(&csq[tid], s_cs[1][tid]);
    }
  }
}

// ---------------- BN apply ----------------
__global__ void k_bn16(_Float16* __restrict__ h, const float* __restrict__ csum,
                       const float* __restrict__ csq, const float* __restrict__ gg,
                       const float* __restrict__ be, int n, int fo, int relu) {
  int i = blockIdx.x * 256 + threadIdx.x;
  int total = (n * fo) >> 3;
  if (i >= total) return;
  int c0 = (i << 3) % fo;
  float invn = 1.f / (float)n;
  f16x8 v = *(const f16x8*)&h[(size_t)i << 3];
  f16x8 o;
#pragma unroll
  for (int j = 0; j < 8; ++j) {
    int c = c0 + j;
    float mu = csum[c] * invn;
    float var = csq[c] * invn - mu * mu;
    float rs = rsqrtf(var + 1e-5f);
    float x = ((float)v[j] - mu) * rs * gg[c] + be[c];
    if (relu) x = fmaxf(x, 0.f);
    o[j] = (_Float16)x;
  }
  *(f16x8*)&h[(size_t)i << 3] = o;
}

__global__ void k_bnf(float* __restrict__ h, const float* __restrict__ csum,
                      const float* __restrict__ csq, const float* __restrict__ gg,
                      const float* __restrict__ be, int n, int fo, int relu) {
  int i = blockIdx.x * 256 + threadIdx.x;
  if (i >= n * fo) return;
  int c = i % fo;
  float invn = 1.f / (float)n;
  float mu = csum[c] * invn;
  float var = csq[c] * invn - mu * mu;
  float rs = rsqrtf(var + 1e-5f);
  float v = (h[i] - mu) * rs * gg[c] + be[c];
  if (relu) v = fmaxf(v, 0.f);
  h[i] = v;
}

// ---------------- pooling + head ----------------
__global__ void k_pool(const float* __restrict__ h, const int* __restrict__ batch,
                       float* __restrict__ zsum, float* __restrict__ gcnt, int n) {
  __shared__ float sv[NGRAPH * 20];
  __shared__ float sc[NGRAPH];
  int tid = threadIdx.x;
  for (int u = tid; u < NGRAPH * 20; u += 256) sv[u] = 0.f;
  if (tid < NGRAPH) sc[tid] = 0.f;
  __syncthreads();
  int i = blockIdx.x * 256 + tid;
  if (i < n) {
    int g = batch[i];
    atomicAdd(&sc[g], 1.f);
    for (int j = 0; j < 20; ++j) atomicAdd(&sv[g * 20 + j], h[(size_t)i * 20 + j]);
  }
  __syncthreads();
  if (tid < NGRAPH && sc[tid] != 0.f) {
    atomicAdd(&gcnt[tid], sc[tid]);
    for (int j = 0; j < 20; ++j) atomicAdd(&zsum[tid * 20 + j], sv[tid * 20 + j]);
  }
}

__global__ void k_head(const float* __restrict__ zsum, const float* __restrict__ gcnt,
                       const float* __restrict__ wl, const float* __restrict__ bl,
                       float* __restrict__ out) {
  int g = threadIdx.x;
  if (g >= NGRAPH) return;
  float z[20];
  float icg = 1.f / fmaxf(gcnt[g], 1.f);
#pragma unroll
  for (int j = 0; j < 20; ++j) {
    z[j] = zsum[g * 20 + j] * icg;
    out[NGRAPH * 11 + g * 20 + j] = z[j];  // second output: z
  }
  float lo[11];
#pragma unroll
  for (int o = 0; o < 11; ++o) {
    float a = bl[o];
    for (int j = 0; j < 20; ++j) a += z[j] * wl[j * 11 + o];
    lo[o] = a;
  }
  float m = lo[0];
  for (int o = 1; o < 11; ++o) m = fmaxf(m, lo[o]);
  float s = 0.f;
  for (int o = 0; o < 11; ++o) { lo[o] = expf(lo[o] - m); s += lo[o]; }
  float is = 1.f / s;
  for (int o = 0; o < 11; ++o) out[g * 11 + o] = lo[o] * is;  // first output: softmax
}

// ---------------- launch ----------------
static inline char* carve(char*& p, size_t bytes) {
  char* r = p;
  p += (bytes + 255) & ~(size_t)255;
  return r;
}

extern "C" void kernel_launch(void* const* d_in, const int* in_sizes, int n_in,
                              void* d_out, int out_size, void* d_ws, size_t ws_size,
                              hipStream_t stream) {
  const float* x = (const float*)d_in[0];
  const int* ei = (const int*)d_in[1];
  const int* batch = (const int*)d_in[2];
  const float* W0 = (const float*)d_in[3];
  const float* b0 = (const float*)d_in[4];
  const float* W1 = (const float*)d_in[5];
  const float* b1 = (const float*)d_in[6];
  const float* W2 = (const float*)d_in[7];
  const float* b2 = (const float*)d_in[8];
  const float* W3 = (const float*)d_in[9];
  const float* b3 = (const float*)d_in[10];
  const float* g0 = (const float*)d_in[11];
  const float* be0 = (const float*)d_in[12];
  const float* g1 = (const float*)d_in[13];
  const float* be1 = (const float*)d_in[14];
  const float* g2 = (const float*)d_in[15];
  const float* be2 = (const float*)d_in[16];
  const float* wl = (const float*)d_in[17];
  const float* bl = (const float*)d_in[18];
  float* out = (float*)d_out;

  const int E = in_sizes[1] / 2;       // 3200000
  const int NB = (NN + 255) / 256;     // 391
  const int BCAP = E / NPART + 65536;  // bucket capacity

  char* p = (char*)d_ws;
  int* cnt = (int*)carve(p, (size_t)NN * 4);
  int* row_ptr = (int*)carve(p, (size_t)(NN + 1) * 4);
  int* bsum = (int*)carve(p, 2048);
  int* boff = (int*)carve(p, 2048);
  int* bcur = (int*)carve(p, 256);
  int* colv = (int*)carve(p, (size_t)E * 4);
  unsigned long long* bkt = (unsigned long long*)carve(p, (size_t)NPART * BCAP * 8);
  int* dhist = (int*)carve(p, (size_t)NPART * DB * NPB * 4);
  float* invd = (float*)carve(p, (size_t)NN * 4);
  float* s1v = (float*)carve(p, (size_t)NN * 4);
  float* s2v = (float*)carve(p, (size_t)NN * 4);
  _Float16* Wt0 = (_Float16*)carve(p, (size_t)96 * 832 * 2);
  _Float16* Wt1 = (_Float16*)carve(p, (size_t)64 * 1248 * 2);
  _Float16* Wt2 = (_Float16*)carve(p, (size_t)32 * 832 * 2);
  _Float16* Wt3 = (_Float16*)carve(p, (size_t)32 * 416 * 2);
  float* cs = (float*)carve(p, 192 * 4);
  float* csum = cs;
  float* csq = cs + 96;
  float* pacc = (float*)carve(p, (NGRAPH * 20 + NGRAPH) * 4);
  float* zsum = pacc;
  float* gcnt = pacc + NGRAPH * 20;
  _Float16* x16 = (_Float16*)carve(p, (size_t)NN * 64 * 2);
  _Float16* hA16 = (_Float16*)carve(p, (size_t)NN * 96 * 2);
  _Float16* hB16 = (_Float16*)carve(p, (size_t)NN * 96 * 2);
  _Float16* aggb = (_Float16*)carve(p, (size_t)NN * 4 * 96 * 2);
  float* h3 = (float*)x16;  // reuse: x16 dead after L0

  // CSR: wave-private bin -> LDS hist (+L2 prime) -> slice-scan -> atomic-free fill
  hipMemsetAsync(bcur, 0, 256, stream);
  hipMemsetAsync(pacc, 0, (NGRAPH * 20 + NGRAPH) * 4, stream);
  k_binstage<<<768, 256, 0, stream>>>(ei, bcur, bkt, BCAP, E);
  k_dhist<<<NPART * DB, 256, 0, stream>>>(bkt, bcur, BCAP, dhist);
  k_mergesum<<<NB, 256, 0, stream>>>(dhist, cnt, bsum, NN);
  k_scanb<<<1, 512, 0, stream>>>(bsum, boff, NB);
  k_scatter<<<NB, 256, 0, stream>>>(cnt, boff, row_ptr, NN, E);
  k_nodesc<<<NB, 256, 0, stream>>>(cnt, invd, s1v, s2v, NN);
  k_binfill<<<NPART * DB, 256, 0, stream>>>(bkt, bcur, BCAP, dhist, row_ptr, colv);

  // fp16 swizzled weights + fp16 x
  k_wtprep<<<(96 * 832 + 255) / 256, 256, 0, stream>>>(W0, Wt0, 832, 96, 96);
  k_wtprep<<<(64 * 1248 + 255) / 256, 256, 0, stream>>>(W1, Wt1, 1248, 64, 64);
  k_wtprep<<<(32 * 832 + 255) / 256, 256, 0, stream>>>(W2, Wt2, 832, 32, 32);
  k_wtprep<<<(32 * 416 + 255) / 256, 256, 0, stream>>>(W3, Wt3, 416, 20, 32);
  k_xconv<<<(NN * 64 + 255) / 256, 256, 0, stream>>>(x, x16, NN * 64);

  const int GP = NN / 32;  // 3125

  // Layer 0: (64 -> 96), BN + ReLU (stats fused in mlp)
  hipMemsetAsync(cs, 0, 192 * 4, stream);
  k_agg<64, 6><<<GP, 256, 0, stream>>>(x16, row_ptr, colv, invd, aggb);
  k_mlp<64, 96, 96, false, true, _Float16><<<GP, 256, 0, stream>>>(x16, aggb, s1v, s2v, Wt0, b0, hA16, csum, csq);
  k_bn16<<<(NN * 96 / 8 + 255) / 256, 256, 0, stream>>>(hA16, csum, csq, g0, be0, NN, 96, 1);

  // Layer 1: (96 -> 64), BN + ReLU
  hipMemsetAsync(cs, 0, 192 * 4, stream);
  k_agg<96, 4><<<GP, 256, 0, stream>>>(hA16, row_ptr, colv, invd, aggb);
  k_mlp<96, 64, 64, false, true, _Float16><<<GP, 256, 0, stream>>>(hA16, aggb, s1v, s2v, Wt1, b1, hB16, csum, csq);
  k_bn16<<<(NN * 64 / 8 + 255) / 256, 256, 0, stream>>>(hB16, csum, csq, g1, be1, NN, 64, 1);

  // Layer 2: (64 -> 32), ReLU fused, no BN
  k_agg<64, 6><<<GP, 256, 0, stream>>>(hB16, row_ptr, colv, invd, aggb);
  k_mlp<64, 32, 32, true, false, _Float16><<<GP, 256, 0, stream>>>(hB16, aggb, s1v, s2v, Wt2, b2, hA16, csum, csq);

  // Layer 3: (32 -> 20), BN (no ReLU), fp32 out
  hipMemsetAsync(cs, 0, 192 * 4, stream);
  k_agg<32, 8><<<GP, 256, 0, stream>>>(hA16, row_ptr, colv, invd, aggb);
  k_mlp<32, 20, 32, false, true, float><<<GP, 256, 0, stream>>>(hA16, aggb, s1v, s2v, Wt3, b3, h3, csum, csq);
  k_bnf<<<(NN * 20 + 255) / 256, 256, 0, stream>>>(h3, csum, csq, g2, be2, NN, 20, 0);

  // global mean pool + linear + softmax
  k_pool<<<NB, 256, 0, stream>>>(h3, batch, zsum, gcnt, NN);
  k_head<<<1, 64, 0, stream>>>(zsum, gcnt, wl, bl, out);
}

// Round 13
// 971.030 us; speedup vs baseline: 1.3083x; 1.3083x over previous
//
#include <hip/hip_runtime.h>

#define NN 100000
#define NGRAPH 64
#define NPART 8
#define NPB 12500
#define DB 16
#define NSB 768
#define AVGLOG 3.4965075614664802f

using f32x4 = __attribute__((ext_vector_type(4))) float;
using f16x8 = __attribute__((ext_vector_type(8))) _Float16;
using f16x4 = __attribute__((ext_vector_type(4))) _Float16;

// ---------------- CSR build ----------------
// Pass 1: block-cooperative LDS-staged binning, wave-aggregated append
// (r11 version: 148us measured, 0 LDS conflicts, WRITE 25MB).
__global__ __launch_bounds__(256) void k_binstage(
    const int* __restrict__ ei, int* __restrict__ bcur,
    unsigned long long* __restrict__ bkt, int cap, int E) {
  __shared__ unsigned long long s_bkt[NPART][NSB];
  __shared__ int s_cnt[NPART], s_base[NPART];
  const int tid = threadIdx.x;
  const int lane = tid & 63;
  if (tid < NPART) s_cnt[tid] = 0;
  __syncthreads();
  const int total_ch = (E + 255) / 256;
  for (int ch = blockIdx.x; ch < total_ch; ch += gridDim.x) {
    int e = ch * 256 + tid;
    int b = -1;
    unsigned long long v = 0;
    if (e < E) {
      int d = __builtin_nontemporal_load(&ei[E + e]);
      int s = __builtin_nontemporal_load(&ei[e]);
      b = d / NPB;
      v = ((unsigned long long)(unsigned)d << 32) | (unsigned)s;
    }
#pragma unroll
    for (int b0 = 0; b0 < NPART; ++b0) {
      unsigned long long mask = __ballot(b == b0);
      if (mask) {
        int lead = __ffsll((long long)mask) - 1;
        int base = 0;
        if (lane == lead) base = atomicAdd(&s_cnt[b0], __popcll(mask));
        base = __shfl(base, lead);
        if (b == b0) {
          int off = __popcll(mask & ((1ull << lane) - 1ull));
          s_bkt[b0][base + off] = v;
        }
      }
    }
    __syncthreads();
#pragma unroll
    for (int b0 = 0; b0 < NPART; ++b0) {
      int c = s_cnt[b0];                     // block-uniform
      int nfl = (c >= 512) ? (c & ~255) : 0; // flush multiple of 256
      if (nfl) {
        if (tid == 0) s_base[b0] = atomicAdd(&bcur[b0], nfl);
        __syncthreads();
        int base = s_base[b0];
        for (int i = tid; i < nfl; i += 256)
          bkt[(size_t)b0 * cap + base + i] = s_bkt[b0][i];
        __syncthreads();
        int rem = c - nfl;                   // rem < 256 <= nfl -> no overlap
        if (tid < rem) s_bkt[b0][tid] = s_bkt[b0][nfl + tid];
        if (tid == 0) s_cnt[b0] = rem;
        __syncthreads();
      }
    }
  }
#pragma unroll
  for (int b0 = 0; b0 < NPART; ++b0) {
    int c = s_cnt[b0];
    if (c) {
      if (tid == 0) s_base[b0] = atomicAdd(&bcur[b0], c);
      __syncthreads();
      int base = s_base[b0];
      for (int i = tid; i < c; i += 256)
        bkt[(size_t)b0 * cap + base + i] = s_bkt[b0][i];
    }
    __syncthreads();
  }
}

// Degree histogram per (partition, slice): LDS hist, coalesced slice write.
// Normal loads (no nt) so the chunk primes this XCD's L2 for k_binfill.
__global__ __launch_bounds__(256) void k_dhist(
    const unsigned long long* __restrict__ bkt, const int* __restrict__ bcur,
    int cap, int* __restrict__ dhist) {
  __shared__ int hist[NPB];
  const int p = blockIdx.x & (NPART - 1);
  const int b = blockIdx.x >> 3;
  const int tid = threadIdx.x;
  for (int i = tid; i < NPB; i += 256) hist[i] = 0;
  __syncthreads();
  const int n = bcur[p];
  const int chunk = (n + DB - 1) / DB;
  const int lo = b * chunk, hi = min(n, lo + chunk);
  const unsigned long long* base = bkt + (size_t)p * cap;
  const int plo = p * NPB;
  for (int i = lo + tid; i < hi; i += 256) {
    unsigned long long v = base[i];
    atomicAdd(&hist[(int)(v >> 32) - plo], 1);
  }
  __syncthreads();
  int* dst = dhist + ((size_t)p * DB + b) * NPB;
  for (int i = tid; i < NPB; i += 256) dst[i] = hist[i];
}

// In-place exclusive slice-scan of dhist; cnt[i] = total; block sums for scan.
__global__ void k_mergesum(int* __restrict__ dhist, int* __restrict__ cnt,
                           int* __restrict__ bsum, int n) {
  __shared__ int s[256];
  int i = blockIdx.x * 256 + threadIdx.x;
  int acc = 0;
  if (i < n) {
    int p = i / NPB, li = i - p * NPB;
    int* hb = dhist + (size_t)p * DB * NPB + li;
#pragma unroll
    for (int b = 0; b < DB; ++b) {
      int t = hb[b * NPB];
      hb[b * NPB] = acc;
      acc += t;
    }
    cnt[i] = acc;
  }
  s[threadIdx.x] = acc;
  __syncthreads();
  for (int off = 128; off > 0; off >>= 1) {
    if (threadIdx.x < off) s[threadIdx.x] += s[threadIdx.x + off];
    __syncthreads();
  }
  if (threadIdx.x == 0) bsum[blockIdx.x] = s[0];
}

// Pass 2: ZERO global atomics. rank[li] preloaded = row_ptr + slice offset;
// per edge one LDS atomic gives the exact final colv position.
__global__ __launch_bounds__(256) void k_binfill(
    const unsigned long long* __restrict__ bkt, const int* __restrict__ bcur,
    int cap, const int* __restrict__ dhist, const int* __restrict__ row_ptr,
    int* __restrict__ colv) {
  __shared__ int rank[NPB];
  const int p = blockIdx.x & (NPART - 1);
  const int b = blockIdx.x >> 3;
  const int tid = threadIdx.x;
  const int plo = p * NPB;
  const int* soff = dhist + ((size_t)p * DB + b) * NPB;
  for (int li = tid; li < NPB; li += 256) rank[li] = row_ptr[plo + li] + soff[li];
  __syncthreads();
  const int n = bcur[p];
  const int chunk = (n + DB - 1) / DB;
  const int lo = b * chunk, hi = min(n, lo + chunk);
  const unsigned long long* base = bkt + (size_t)p * cap;
  for (int i = lo + tid; i < hi; i += 256) {
    unsigned long long v = base[i];
    int d = (int)(v >> 32);
    int s = (int)(v & 0xffffffffu);
    int pos = atomicAdd(&rank[d - plo], 1);
    colv[pos] = s;
  }
}

__global__ void k_scanb(const int* __restrict__ bsum, int* __restrict__ boff, int nb) {
  __shared__ int s[512];
  int t = threadIdx.x;
  int v = (t < nb) ? bsum[t] : 0;
  s[t] = v;
  __syncthreads();
  for (int off = 1; off < 512; off <<= 1) {
    int u = (t >= off) ? s[t - off] : 0;
    __syncthreads();
    s[t] += u;
    __syncthreads();
  }
  if (t < nb) boff[t] = s[t] - v;  // exclusive block offsets
}

__global__ void k_scatter(const int* __restrict__ cnt, const int* __restrict__ boff,
                          int* __restrict__ row_ptr, int n, int etot) {
  __shared__ int s[256];
  int i = blockIdx.x * 256 + threadIdx.x;
  int v = (i < n) ? cnt[i] : 0;
  s[threadIdx.x] = v;
  __syncthreads();
  for (int off = 1; off < 256; off <<= 1) {
    int u = (threadIdx.x >= off) ? s[threadIdx.x - off] : 0;
    __syncthreads();
    s[threadIdx.x] += u;
    __syncthreads();
  }
  if (i < n) row_ptr[i] = boff[blockIdx.x] + s[threadIdx.x] - v;
  if (i == 0) row_ptr[n] = etot;
}

__global__ void k_nodesc(const int* __restrict__ cnt, float* __restrict__ invd,
                         float* __restrict__ s1v, float* __restrict__ s2v, int n) {
  int i = blockIdx.x * 256 + threadIdx.x;
  if (i >= n) return;
  float degc = fmaxf((float)cnt[i], 1.f);
  invd[i] = 1.f / degc;
  float ld = logf(degc + 1.f);
  s1v[i] = ld * (1.f / AVGLOG);
  s2v[i] = AVGLOG / ld;
}

// W [K][FO] fp32 -> fp16 in MFMA B-fragment order
__global__ void k_wtprep(const float* __restrict__ W, _Float16* __restrict__ Wt,
                         int K, int FO, int FOP) {
  int i = blockIdx.x * 256 + threadIdx.x;
  if (i >= FOP * K) return;
  int nn = i / K, k = i - nn * K;
  float v = (nn < FO) ? W[k * FO + nn] : 0.f;
  int NT = FOP >> 4;
  int kt = k >> 5, q = (k >> 3) & 3, j = k & 7;
  int nt = nn >> 4, m = nn & 15;
  size_t idx = (((size_t)kt * NT + nt) * 64 + (q * 16 + m)) * 8 + j;
  Wt[idx] = (_Float16)v;
}

__global__ void k_xconv(const float* __restrict__ x, _Float16* __restrict__ x16, int n) {
  int i = blockIdx.x * 256 + threadIdx.x;
  if (i < n) x16[i] = (_Float16)x[i];
}

// ---------------- Phase A: gather/reduce; writes agg in MFMA A-frag order ----------------
template <int F, int WPE>
__launch_bounds__(256, WPE)
__global__ void k_agg(const _Float16* __restrict__ hin, const int* __restrict__ row_ptr,
                      const int* __restrict__ colv, const float* __restrict__ invd,
                      _Float16* __restrict__ agg) {
  const int tid = threadIdx.x;
  const int r = tid >> 3, g = tid & 7;
  const int n = blockIdx.x * 32 + r;
  const int e0 = row_ptr[n], e1 = row_ptr[n + 1];
  constexpr int SEG = F / 8;
  constexpr int SEG4 = SEG / 4;
  constexpr int KTA = F / 8;
  float sm[SEG], sq[SEG], mn[SEG], mx[SEG];
  const float FINF = __builtin_inff();
#pragma unroll
  for (int j = 0; j < SEG; ++j) { sm[j] = 0.f; sq[j] = 0.f; mn[j] = FINF; mx[j] = -FINF; }
  int e = e0;
  for (; e + 1 < e1; e += 2) {
    int sA = colv[e], sB = colv[e + 1];
    const f16x4* ra = (const f16x4*)(hin + (size_t)sA * F + g * SEG);
    const f16x4* rb = (const f16x4*)(hin + (size_t)sB * F + g * SEG);
#pragma unroll
    for (int c = 0; c < SEG4; ++c) {
      f16x4 va = ra[c], vb = rb[c];
#pragma unroll
      for (int l = 0; l < 4; ++l) {
        float av = (float)va[l], bv = (float)vb[l];
        int j = 4 * c + l;
        sm[j] += av + bv;
        sq[j] += av * av + bv * bv;
        mn[j] = fminf(mn[j], fminf(av, bv));
        mx[j] = fmaxf(mx[j], fmaxf(av, bv));
      }
    }
  }
  if (e < e1) {
    int sA = colv[e];
    const f16x4* ra = (const f16x4*)(hin + (size_t)sA * F + g * SEG);
#pragma unroll
    for (int c = 0; c < SEG4; ++c) {
      f16x4 va = ra[c];
#pragma unroll
      for (int l = 0; l < 4; ++l) {
        float av = (float)va[l];
        int j = 4 * c + l;
        sm[j] += av;
        sq[j] += av * av;
        mn[j] = fminf(mn[j], av);
        mx[j] = fmaxf(mx[j], av);
      }
    }
  }
  float iv = invd[n];
  bool has = (e1 > e0);
  const int m = n & 15;
  const size_t tb = (size_t)(n >> 4) * KTA;
#pragma unroll
  for (int c = 0; c < SEG4; ++c) {
    f16x4 vals[4];
#pragma unroll
    for (int l = 0; l < 4; ++l) {
      int j = 4 * c + l;
      float mean = sm[j] * iv;
      float var = sq[j] * iv - mean * mean;
      float sd = sqrtf(fmaxf(var, 0.f) + 1e-5f);
      vals[0][l] = (_Float16)mean;
      vals[1][l] = has ? (_Float16)mn[j] : (_Float16)0.f;
      vals[2][l] = has ? (_Float16)mx[j] : (_Float16)0.f;
      vals[3][l] = (_Float16)sd;
    }
    int f0 = g * SEG + 4 * c;
#pragma unroll
    for (int a = 0; a < 4; ++a) {
      int kk0 = a * F + f0;
      int kt = kk0 >> 5, q = (kk0 >> 3) & 3, j0 = kk0 & 7;
      *(f16x4*)(agg + (tb + kt) * 512 + (q * 16 + m) * 8 + j0) = vals[a];
    }
  }
}

// ---------------- Phase B: global-direct MFMA GEMM + fused BN column stats ----------------
#define MFMA16(a, b, c) __builtin_amdgcn_mfma_f32_16x16x32_f16(a, b, c, 0, 0, 0)

template <int F, int FO, int FOP, bool RELU, bool STATS, typename OT>
__launch_bounds__(256)
__global__ void k_mlp(const _Float16* __restrict__ hin, const _Float16* __restrict__ agg,
                      const float* __restrict__ s1g, const float* __restrict__ s2g,
                      const _Float16* __restrict__ Wt, const float* __restrict__ bias,
                      OT* __restrict__ hout, float* __restrict__ csum,
                      float* __restrict__ csq) {
  constexpr int F32 = F / 32;
  constexpr int KTA = F / 8;
  constexpr int NT = FOP / 16;
  constexpr int PPW = (2 * NT) / 4;
  constexpr int XW = F + 8;
  __shared__ __align__(16) _Float16 s_x[32][XW];
  __shared__ float s_cs[2][FOP];

  const int tid = threadIdx.x;
  const int n0 = blockIdx.x * 32;

  for (int idx = tid; idx < 32 * (F / 8); idx += 256) {
    int r = idx / (F / 8), c = idx % (F / 8);
    *(f16x8*)&s_x[r][8 * c] = *(const f16x8*)&hin[(size_t)(n0 + r) * F + 8 * c];
  }
  if (STATS)
    for (int u = tid; u < 2 * FOP; u += 256) (&s_cs[0][0])[u] = 0.f;
  __syncthreads();

  const int w = tid >> 6, ln = tid & 63;
  const int lm = ln & 15, q = ln >> 4;
  const int mt = w & 1;
  const int arow = mt * 16 + lm;
  f32x4 acc0[PPW], acc1[PPW], acc2[PPW];
#pragma unroll
  for (int i = 0; i < PPW; ++i)
#pragma unroll
    for (int t = 0; t < 4; ++t) { acc0[i][t] = 0.f; acc1[i][t] = 0.f; acc2[i][t] = 0.f; }

#pragma unroll
  for (int kt = 0; kt < F32; ++kt) {
    f16x8 a = *(const f16x8*)&s_x[arow][kt * 32 + 8 * q];
#pragma unroll
    for (int i = 0; i < PPW; ++i) {
      int nt = (w >> 1) + 2 * i;
      f16x8 b = *(const f16x8*)&Wt[(((size_t)kt * NT + nt) * 64 + ln) * 8];
      acc0[i] = MFMA16(a, b, acc0[i]);
    }
  }
  const size_t atb = (size_t)(blockIdx.x * 2 + mt) * KTA;
#pragma unroll
  for (int kt = 0; kt < KTA; ++kt) {
    f16x8 a = *(const f16x8*)&agg[(atb + kt) * 512 + ln * 8];
#pragma unroll
    for (int i = 0; i < PPW; ++i) {
      int nt = (w >> 1) + 2 * i;
      f16x8 b0 = *(const f16x8*)&Wt[(((size_t)(F32 + kt) * NT + nt) * 64 + ln) * 8];
      acc0[i] = MFMA16(a, b0, acc0[i]);
      f16x8 b1 = *(const f16x8*)&Wt[(((size_t)(F32 + KTA + kt) * NT + nt) * 64 + ln) * 8];
      acc1[i] = MFMA16(a, b1, acc1[i]);
      f16x8 b2 = *(const f16x8*)&Wt[(((size_t)(F32 + 2 * KTA + kt) * NT + nt) * 64 + ln) * 8];
      acc2[i] = MFMA16(a, b2, acc2[i]);
    }
  }

  float s1r[4], s2r[4];
#pragma unroll
  for (int t = 0; t < 4; ++t) {
    int node = n0 + mt * 16 + q * 4 + t;
    s1r[t] = s1g[node];
    s2r[t] = s2g[node];
  }
#pragma unroll
  for (int i = 0; i < PPW; ++i) {
    int nt = (w >> 1) + 2 * i;
    int ncol = nt * 16 + lm;
    if (FOP == FO || ncol < FO) {
      float bs = bias[ncol];
      float cs = 0.f, cq = 0.f;
#pragma unroll
      for (int t = 0; t < 4; ++t) {
        int node = n0 + mt * 16 + q * 4 + t;
        float v = acc0[i][t] + s1r[t] * acc1[i][t] + s2r[t] * acc2[i][t] + bs;
        if (RELU) v = fmaxf(v, 0.f);
        hout[(size_t)node * FO + ncol] = (OT)v;
        cs += v;
        cq += v * v;
      }
      if (STATS) {
        atomicAdd(&s_cs[0][ncol], cs);
        atomicAdd(&s_cs[1][ncol], cq);
      }
    }
  }
  if (STATS) {
    __syncthreads();
    if (tid < FO) {
      atomicAdd(&csum[tid], s_cs[0][tid]);
      atomicAdd(&csq[tid], s_cs[1][tid]);
    }
  }
}

// ---------------- BN apply ----------------
__global__ void k_bn16(_Float16* __restrict__ h, const float* __restrict__ csum,
                       const float* __restrict__ csq, const float* __restrict__ gg,
                       const float* __restrict__ be, int n, int fo, int relu) {
  int i = blockIdx.x * 256 + threadIdx.x;
  int total = (n * fo) >> 3;
  if (i >= total) return;
  int c0 = (i << 3) % fo;
  float invn = 1.f / (float)n;
  f16x8 v = *(const f16x8*)&h[(size_t)i << 3];
  f16x8 o;
#pragma unroll
  for (int j = 0; j < 8; ++j) {
    int c = c0 + j;
    float mu = csum[c] * invn;
    float var = csq[c] * invn - mu * mu;
    float rs = rsqrtf(var + 1e-5f);
    float x = ((float)v[j] - mu) * rs * gg[c] + be[c];
    if (relu) x = fmaxf(x, 0.f);
    o[j] = (_Float16)x;
  }
  *(f16x8*)&h[(size_t)i << 3] = o;
}

__global__ void k_bnf(float* __restrict__ h, const float* __restrict__ csum,
                      const float* __restrict__ csq, const float* __restrict__ gg,
                      const float* __restrict__ be, int n, int fo, int relu) {
  int i = blockIdx.x * 256 + threadIdx.x;
  if (i >= n * fo) return;
  int c = i % fo;
  float invn = 1.f / (float)n;
  float mu = csum[c] * invn;
  float var = csq[c] * invn - mu * mu;
  float rs = rsqrtf(var + 1e-5f);
  float v = (h[i] - mu) * rs * gg[c] + be[c];
  if (relu) v = fmaxf(v, 0.f);
  h[i] = v;
}

// ---------------- pooling + head ----------------
__global__ void k_pool(const float* __restrict__ h, const int* __restrict__ batch,
                       float* __restrict__ zsum, float* __restrict__ gcnt, int n) {
  __shared__ float sv[NGRAPH * 20];
  __shared__ float sc[NGRAPH];
  int tid = threadIdx.x;
  for (int u = tid; u < NGRAPH * 20; u += 256) sv[u] = 0.f;
  if (tid < NGRAPH) sc[tid] = 0.f;
  __syncthreads();
  int i = blockIdx.x * 256 + tid;
  if (i < n) {
    int g = batch[i];
    atomicAdd(&sc[g], 1.f);
    for (int j = 0; j < 20; ++j) atomicAdd(&sv[g * 20 + j], h[(size_t)i * 20 + j]);
  }
  __syncthreads();
  if (tid < NGRAPH && sc[tid] != 0.f) {
    atomicAdd(&gcnt[tid], sc[tid]);
    for (int j = 0; j < 20; ++j) atomicAdd(&zsum[tid * 20 + j], sv[tid * 20 + j]);
  }
}

__global__ void k_head(const float* __restrict__ zsum, const float* __restrict__ gcnt,
                       const float* __restrict__ wl, const float* __restrict__ bl,
                       float* __restrict__ out) {
  int g = threadIdx.x;
  if (g >= NGRAPH) return;
  float z[20];
  float icg = 1.f / fmaxf(gcnt[g], 1.f);
#pragma unroll
  for (int j = 0; j < 20; ++j) {
    z[j] = zsum[g * 20 + j] * icg;
    out[NGRAPH * 11 + g * 20 + j] = z[j];  // second output: z
  }
  float lo[11];
#pragma unroll
  for (int o = 0; o < 11; ++o) {
    float a = bl[o];
    for (int j = 0; j < 20; ++j) a += z[j] * wl[j * 11 + o];
    lo[o] = a;
  }
  float m = lo[0];
  for (int o = 1; o < 11; ++o) m = fmaxf(m, lo[o]);
  float s = 0.f;
  for (int o = 0; o < 11; ++o) { lo[o] = expf(lo[o] - m); s += lo[o]; }
  float is = 1.f / s;
  for (int o = 0; o < 11; ++o) out[g * 11 + o] = lo[o] * is;  // first output: softmax
}

// ---------------- launch ----------------
static inline char* carve(char*& p, size_t bytes) {
  char* r = p;
  p += (bytes + 255) & ~(size_t)255;
  return r;
}

extern "C" void kernel_launch(void* const* d_in, const int* in_sizes, int n_in,
                              void* d_out, int out_size, void* d_ws, size_t ws_size,
                              hipStream_t stream) {
  const float* x = (const float*)d_in[0];
  const int* ei = (const int*)d_in[1];
  const int* batch = (const int*)d_in[2];
  const float* W0 = (const float*)d_in[3];
  const float* b0 = (const float*)d_in[4];
  const float* W1 = (const float*)d_in[5];
  const float* b1 = (const float*)d_in[6];
  const float* W2 = (const float*)d_in[7];
  const float* b2 = (const float*)d_in[8];
  const float* W3 = (const float*)d_in[9];
  const float* b3 = (const float*)d_in[10];
  const float* g0 = (const float*)d_in[11];
  const float* be0 = (const float*)d_in[12];
  const float* g1 = (const float*)d_in[13];
  const float* be1 = (const float*)d_in[14];
  const float* g2 = (const float*)d_in[15];
  const float* be2 = (const float*)d_in[16];
  const float* wl = (const float*)d_in[17];
  const float* bl = (const float*)d_in[18];
  float* out = (float*)d_out;

  const int E = in_sizes[1] / 2;       // 3200000
  const int NB = (NN + 255) / 256;     // 391
  const int BCAP = E / NPART + 65536;  // bucket capacity

  char* p = (char*)d_ws;
  int* cnt = (int*)carve(p, (size_t)NN * 4);
  int* row_ptr = (int*)carve(p, (size_t)(NN + 1) * 4);
  int* bsum = (int*)carve(p, 2048);
  int* boff = (int*)carve(p, 2048);
  int* bcur = (int*)carve(p, 256);
  int* colv = (int*)carve(p, (size_t)E * 4);
  unsigned long long* bkt = (unsigned long long*)carve(p, (size_t)NPART * BCAP * 8);
  int* dhist = (int*)carve(p, (size_t)NPART * DB * NPB * 4);
  float* invd = (float*)carve(p, (size_t)NN * 4);
  float* s1v = (float*)carve(p, (size_t)NN * 4);
  float* s2v = (float*)carve(p, (size_t)NN * 4);
  _Float16* Wt0 = (_Float16*)carve(p, (size_t)96 * 832 * 2);
  _Float16* Wt1 = (_Float16*)carve(p, (size_t)64 * 1248 * 2);
  _Float16* Wt2 = (_Float16*)carve(p, (size_t)32 * 832 * 2);
  _Float16* Wt3 = (_Float16*)carve(p, (size_t)32 * 416 * 2);
  float* cs = (float*)carve(p, 192 * 4);
  float* csum = cs;
  float* csq = cs + 96;
  float* pacc = (float*)carve(p, (NGRAPH * 20 + NGRAPH) * 4);
  float* zsum = pacc;
  float* gcnt = pacc + NGRAPH * 20;
  _Float16* x16 = (_Float16*)carve(p, (size_t)NN * 64 * 2);
  _Float16* hA16 = (_Float16*)carve(p, (size_t)NN * 96 * 2);
  _Float16* hB16 = (_Float16*)carve(p, (size_t)NN * 96 * 2);
  _Float16* aggb = (_Float16*)carve(p, (size_t)NN * 4 * 96 * 2);
  float* h3 = (float*)x16;  // reuse: x16 dead after L0

  // CSR: block-coop bin -> LDS hist (+L2 prime) -> slice-scan -> atomic-free fill
  hipMemsetAsync(bcur, 0, 256, stream);
  hipMemsetAsync(pacc, 0, (NGRAPH * 20 + NGRAPH) * 4, stream);
  k_binstage<<<768, 256, 0, stream>>>(ei, bcur, bkt, BCAP, E);
  k_dhist<<<NPART * DB, 256, 0, stream>>>(bkt, bcur, BCAP, dhist);
  k_mergesum<<<NB, 256, 0, stream>>>(dhist, cnt, bsum, NN);
  k_scanb<<<1, 512, 0, stream>>>(bsum, boff, NB);
  k_scatter<<<NB, 256, 0, stream>>>(cnt, boff, row_ptr, NN, E);
  k_nodesc<<<NB, 256, 0, stream>>>(cnt, invd, s1v, s2v, NN);
  k_binfill<<<NPART * DB, 256, 0, stream>>>(bkt, bcur, BCAP, dhist, row_ptr, colv);

  // fp16 swizzled weights + fp16 x
  k_wtprep<<<(96 * 832 + 255) / 256, 256, 0, stream>>>(W0, Wt0, 832, 96, 96);
  k_wtprep<<<(64 * 1248 + 255) / 256, 256, 0, stream>>>(W1, Wt1, 1248, 64, 64);
  k_wtprep<<<(32 * 832 + 255) / 256, 256, 0, stream>>>(W2, Wt2, 832, 32, 32);
  k_wtprep<<<(32 * 416 + 255) / 256, 256, 0, stream>>>(W3, Wt3, 416, 20, 32);
  k_xconv<<<(NN * 64 + 255) / 256, 256, 0, stream>>>(x, x16, NN * 64);

  const int GP = NN / 32;  // 3125

  // Layer 0: (64 -> 96), BN + ReLU (stats fused in mlp)
  hipMemsetAsync(cs, 0, 192 * 4, stream);
  k_agg<64, 6><<<GP, 256, 0, stream>>>(x16, row_ptr, colv, invd, aggb);
  k_mlp<64, 96, 96, false, true, _Float16><<<GP, 256, 0, stream>>>(x16, aggb, s1v, s2v, Wt0, b0, hA16, csum, csq);
  k_bn16<<<(NN * 96 / 8 + 255) / 256, 256, 0, stream>>>(hA16, csum, csq, g0, be0, NN, 96, 1);

  // Layer 1: (96 -> 64), BN + ReLU
  hipMemsetAsync(cs, 0, 192 * 4, stream);
  k_agg<96, 4><<<GP, 256, 0, stream>>>(hA16, row_ptr, colv, invd, aggb);
  k_mlp<96, 64, 64, false, true, _Float16><<<GP, 256, 0, stream>>>(hA16, aggb, s1v, s2v, Wt1, b1, hB16, csum, csq);
  k_bn16<<<(NN * 64 / 8 + 255) / 256, 256, 0, stream>>>(hB16, csum, csq, g1, be1, NN, 64, 1);

  // Layer 2: (64 -> 32), ReLU fused, no BN
  k_agg<64, 6><<<GP, 256, 0, stream>>>(hB16, row_ptr, colv, invd, aggb);
  k_mlp<64, 32, 32, true, false, _Float16><<<GP, 256, 0, stream>>>(hB16, aggb, s1v, s2v, Wt2, b2, hA16, csum, csq);

  // Layer 3: (32 -> 20), BN (no ReLU), fp32 out
  hipMemsetAsync(cs, 0, 192 * 4, stream);
  k_agg<32, 8><<<GP, 256, 0, stream>>>(hA16, row_ptr, colv, invd, aggb);
  k_mlp<32, 20, 32, false, true, float><<<GP, 256, 0, stream>>>(hA16, aggb, s1v, s2v, Wt3, b3, h3, csum, csq);
  k_bnf<<<(NN * 20 + 255) / 256, 256, 0, stream>>>(h3, csum, csq, g2, be2, NN, 20, 0);

  // global mean pool + linear + softmax
  k_pool<<<NB, 256, 0, stream>>>(h3, batch, zsum, gcnt, NN);
  k_head<<<1, 64, 0, stream>>>(zsum, gcnt, wl, bl, out);
}

// Round 14
// 965.771 us; speedup vs baseline: 1.3155x; 1.0054x over previous
//
#include <hip/hip_runtime.h>

#define NN 100000
#define NGRAPH 64
#define NPART 8
#define NPB 12500
#define DB 16
#define NSB 768
#define AVGLOG 3.4965075614664802f

using f32x4 = __attribute__((ext_vector_type(4))) float;
using f16x8 = __attribute__((ext_vector_type(8))) _Float16;
using f16x4 = __attribute__((ext_vector_type(4))) _Float16;

// ---------------- CSR build ----------------
// Pass 1: block-cooperative LDS-staged binning. 512 edges per barrier cycle
// (2/thread); each bucket round = 2 ballots + ONE lane-0 LDS atomic for the
// combined count -> halves both atomic rounds and barrier/flush overhead/edge.
__global__ __launch_bounds__(256) void k_binstage(
    const int* __restrict__ ei, int* __restrict__ bcur,
    unsigned long long* __restrict__ bkt, int cap, int E) {
  __shared__ unsigned long long s_bkt[NPART][NSB];
  __shared__ int s_cnt[NPART], s_base[NPART];
  const int tid = threadIdx.x;
  const int lane = tid & 63;
  if (tid < NPART) s_cnt[tid] = 0;
  __syncthreads();
  const int total_ch = (E + 511) / 512;
  for (int ch = blockIdx.x; ch < total_ch; ch += gridDim.x) {
    int eA = ch * 512 + tid;
    int eB = eA + 256;
    int bA = -1, bB = -1;
    unsigned long long vA = 0, vB = 0;
    if (eA < E) {
      int d = __builtin_nontemporal_load(&ei[E + eA]);
      int s = __builtin_nontemporal_load(&ei[eA]);
      bA = d / NPB;
      vA = ((unsigned long long)(unsigned)d << 32) | (unsigned)s;
    }
    if (eB < E) {
      int d = __builtin_nontemporal_load(&ei[E + eB]);
      int s = __builtin_nontemporal_load(&ei[eB]);
      bB = d / NPB;
      vB = ((unsigned long long)(unsigned)d << 32) | (unsigned)s;
    }
#pragma unroll
    for (int b0 = 0; b0 < NPART; ++b0) {
      unsigned long long mA = __ballot(bA == b0);
      unsigned long long mB = __ballot(bB == b0);
      int cA = __popcll(mA);
      int tot = cA + __popcll(mB);
      if (tot) {  // wave-uniform
        int base = 0;
        if (lane == 0) base = atomicAdd(&s_cnt[b0], tot);
        base = __shfl(base, 0);
        if (bA == b0)
          s_bkt[b0][base + __popcll(mA & ((1ull << lane) - 1ull))] = vA;
        if (bB == b0)
          s_bkt[b0][base + cA + __popcll(mB & ((1ull << lane) - 1ull))] = vB;
      }
    }
    __syncthreads();
#pragma unroll
    for (int b0 = 0; b0 < NPART; ++b0) {
      int c = s_cnt[b0];                     // block-uniform
      int nfl = (c >= 512) ? (c & ~255) : 0; // flush multiple of 256
      if (nfl) {
        if (tid == 0) s_base[b0] = atomicAdd(&bcur[b0], nfl);
        __syncthreads();
        int base = s_base[b0];
        for (int i = tid; i < nfl; i += 256)
          bkt[(size_t)b0 * cap + base + i] = s_bkt[b0][i];
        __syncthreads();
        int rem = c - nfl;                   // rem < 256 <= nfl -> no overlap
        if (tid < rem) s_bkt[b0][tid] = s_bkt[b0][nfl + tid];
        if (tid == 0) s_cnt[b0] = rem;
        __syncthreads();
      }
    }
  }
#pragma unroll
  for (int b0 = 0; b0 < NPART; ++b0) {
    int c = s_cnt[b0];
    if (c) {
      if (tid == 0) s_base[b0] = atomicAdd(&bcur[b0], c);
      __syncthreads();
      int base = s_base[b0];
      for (int i = tid; i < c; i += 256)
        bkt[(size_t)b0 * cap + base + i] = s_bkt[b0][i];
    }
    __syncthreads();
  }
}

// Degree histogram per (partition, slice): LDS hist, coalesced slice write.
__global__ __launch_bounds__(256) void k_dhist(
    const unsigned long long* __restrict__ bkt, const int* __restrict__ bcur,
    int cap, int* __restrict__ dhist) {
  __shared__ int hist[NPB];
  const int p = blockIdx.x & (NPART - 1);
  const int b = blockIdx.x >> 3;
  const int tid = threadIdx.x;
  for (int i = tid; i < NPB; i += 256) hist[i] = 0;
  __syncthreads();
  const int n = bcur[p];
  const int chunk = (n + DB - 1) / DB;
  const int lo = b * chunk, hi = min(n, lo + chunk);
  const unsigned long long* base = bkt + (size_t)p * cap;
  const int plo = p * NPB;
  for (int i = lo + tid; i < hi; i += 256) {
    unsigned long long v = base[i];
    atomicAdd(&hist[(int)(v >> 32) - plo], 1);
  }
  __syncthreads();
  int* dst = dhist + ((size_t)p * DB + b) * NPB;
  for (int i = tid; i < NPB; i += 256) dst[i] = hist[i];
}

// In-place exclusive slice-scan of dhist; cnt[i] = total; block sums for scan.
__global__ void k_mergesum(int* __restrict__ dhist, int* __restrict__ cnt,
                           int* __restrict__ bsum, int n) {
  __shared__ int s[256];
  int i = blockIdx.x * 256 + threadIdx.x;
  int acc = 0;
  if (i < n) {
    int p = i / NPB, li = i - p * NPB;
    int* hb = dhist + (size_t)p * DB * NPB + li;
#pragma unroll
    for (int b = 0; b < DB; ++b) {
      int t = hb[b * NPB];
      hb[b * NPB] = acc;
      acc += t;
    }
    cnt[i] = acc;
  }
  s[threadIdx.x] = acc;
  __syncthreads();
  for (int off = 128; off > 0; off >>= 1) {
    if (threadIdx.x < off) s[threadIdx.x] += s[threadIdx.x + off];
    __syncthreads();
  }
  if (threadIdx.x == 0) bsum[blockIdx.x] = s[0];
}

// Pass 2: ZERO global atomics. rank[li] preloaded = row_ptr + slice offset.
__global__ __launch_bounds__(256) void k_binfill(
    const unsigned long long* __restrict__ bkt, const int* __restrict__ bcur,
    int cap, const int* __restrict__ dhist, const int* __restrict__ row_ptr,
    int* __restrict__ colv) {
  __shared__ int rank[NPB];
  const int p = blockIdx.x & (NPART - 1);
  const int b = blockIdx.x >> 3;
  const int tid = threadIdx.x;
  const int plo = p * NPB;
  const int* soff = dhist + ((size_t)p * DB + b) * NPB;
  for (int li = tid; li < NPB; li += 256) rank[li] = row_ptr[plo + li] + soff[li];
  __syncthreads();
  const int n = bcur[p];
  const int chunk = (n + DB - 1) / DB;
  const int lo = b * chunk, hi = min(n, lo + chunk);
  const unsigned long long* base = bkt + (size_t)p * cap;
  for (int i = lo + tid; i < hi; i += 256) {
    unsigned long long v = base[i];
    int d = (int)(v >> 32);
    int s = (int)(v & 0xffffffffu);
    int pos = atomicAdd(&rank[d - plo], 1);
    colv[pos] = s;
  }
}

__global__ void k_scanb(const int* __restrict__ bsum, int* __restrict__ boff, int nb) {
  __shared__ int s[512];
  int t = threadIdx.x;
  int v = (t < nb) ? bsum[t] : 0;
  s[t] = v;
  __syncthreads();
  for (int off = 1; off < 512; off <<= 1) {
    int u = (t >= off) ? s[t - off] : 0;
    __syncthreads();
    s[t] += u;
    __syncthreads();
  }
  if (t < nb) boff[t] = s[t] - v;  // exclusive block offsets
}

__global__ void k_scatter(const int* __restrict__ cnt, const int* __restrict__ boff,
                          int* __restrict__ row_ptr, int n, int etot) {
  __shared__ int s[256];
  int i = blockIdx.x * 256 + threadIdx.x;
  int v = (i < n) ? cnt[i] : 0;
  s[threadIdx.x] = v;
  __syncthreads();
  for (int off = 1; off < 256; off <<= 1) {
    int u = (threadIdx.x >= off) ? s[threadIdx.x - off] : 0;
    __syncthreads();
    s[threadIdx.x] += u;
    __syncthreads();
  }
  if (i < n) row_ptr[i] = boff[blockIdx.x] + s[threadIdx.x] - v;
  if (i == 0) row_ptr[n] = etot;
}

__global__ void k_nodesc(const int* __restrict__ cnt, float* __restrict__ invd,
                         float* __restrict__ s1v, float* __restrict__ s2v, int n) {
  int i = blockIdx.x * 256 + threadIdx.x;
  if (i >= n) return;
  float degc = fmaxf((float)cnt[i], 1.f);
  invd[i] = 1.f / degc;
  float ld = logf(degc + 1.f);
  s1v[i] = ld * (1.f / AVGLOG);
  s2v[i] = AVGLOG / ld;
}

// W [K][FO] fp32 -> fp16 in MFMA B-fragment order
__global__ void k_wtprep(const float* __restrict__ W, _Float16* __restrict__ Wt,
                         int K, int FO, int FOP) {
  int i = blockIdx.x * 256 + threadIdx.x;
  if (i >= FOP * K) return;
  int nn = i / K, k = i - nn * K;
  float v = (nn < FO) ? W[k * FO + nn] : 0.f;
  int NT = FOP >> 4;
  int kt = k >> 5, q = (k >> 3) & 3, j = k & 7;
  int nt = nn >> 4, m = nn & 15;
  size_t idx = (((size_t)kt * NT + nt) * 64 + (q * 16 + m)) * 8 + j;
  Wt[idx] = (_Float16)v;
}

__global__ void k_xconv(const float* __restrict__ x, _Float16* __restrict__ x16, int n) {
  int i = blockIdx.x * 256 + threadIdx.x;
  if (i < n) x16[i] = (_Float16)x[i];
}

// ---------------- Phase A: gather/reduce; writes agg in MFMA A-frag order ----------------
// F=64: rows 16B-aligned per thread -> single f16x8 load; F=96/32: f16x4 loads.
template <int F, int WPE>
__launch_bounds__(256, WPE)
__global__ void k_agg(const _Float16* __restrict__ hin, const int* __restrict__ row_ptr,
                      const int* __restrict__ colv, const float* __restrict__ invd,
                      _Float16* __restrict__ agg) {
  const int tid = threadIdx.x;
  const int r = tid >> 3, g = tid & 7;
  const int n = blockIdx.x * 32 + r;
  const int e0 = row_ptr[n], e1 = row_ptr[n + 1];
  constexpr int SEG = F / 8;
  constexpr int N8 = (SEG % 8 == 0) ? SEG / 8 : 0;   // f16x8 loads
  constexpr int N4 = (SEG % 8 == 0) ? 0 : SEG / 4;   // f16x4 loads
  constexpr int KTA = F / 8;
  float sm[SEG], sq[SEG], mn[SEG], mx[SEG];
  const float FINF = __builtin_inff();
#pragma unroll
  for (int j = 0; j < SEG; ++j) { sm[j] = 0.f; sq[j] = 0.f; mn[j] = FINF; mx[j] = -FINF; }
  int e = e0;
  for (; e + 1 < e1; e += 2) {
    const _Float16* ra = hin + (size_t)colv[e] * F + g * SEG;
    const _Float16* rb = hin + (size_t)colv[e + 1] * F + g * SEG;
    f16x8 a8[N8 ? N8 : 1], b8[N8 ? N8 : 1];
    f16x4 a4[N4 ? N4 : 1], b4[N4 ? N4 : 1];
    if (N8) {
#pragma unroll
      for (int c = 0; c < N8; ++c) { a8[c] = ((const f16x8*)ra)[c]; b8[c] = ((const f16x8*)rb)[c]; }
    } else {
#pragma unroll
      for (int c = 0; c < N4; ++c) { a4[c] = ((const f16x4*)ra)[c]; b4[c] = ((const f16x4*)rb)[c]; }
    }
#pragma unroll
    for (int j = 0; j < SEG; ++j) {
      float av = N8 ? (float)a8[j / 8][j % 8] : (float)a4[j / 4][j % 4];
      float bv = N8 ? (float)b8[j / 8][j % 8] : (float)b4[j / 4][j % 4];
      sm[j] += av + bv;
      sq[j] += av * av + bv * bv;
      mn[j] = fminf(mn[j], fminf(av, bv));
      mx[j] = fmaxf(mx[j], fmaxf(av, bv));
    }
  }
  if (e < e1) {
    const _Float16* ra = hin + (size_t)colv[e] * F + g * SEG;
    f16x8 a8[N8 ? N8 : 1];
    f16x4 a4[N4 ? N4 : 1];
    if (N8) {
#pragma unroll
      for (int c = 0; c < N8; ++c) a8[c] = ((const f16x8*)ra)[c];
    } else {
#pragma unroll
      for (int c = 0; c < N4; ++c) a4[c] = ((const f16x4*)ra)[c];
    }
#pragma unroll
    for (int j = 0; j < SEG; ++j) {
      float av = N8 ? (float)a8[j / 8][j % 8] : (float)a4[j / 4][j % 4];
      sm[j] += av;
      sq[j] += av * av;
      mn[j] = fminf(mn[j], av);
      mx[j] = fmaxf(mx[j], av);
    }
  }
  float iv = invd[n];
  bool has = (e1 > e0);
  const int m = n & 15;
  const size_t tb = (size_t)(n >> 4) * KTA;
#pragma unroll
  for (int c = 0; c < SEG / 4; ++c) {
    f16x4 vals[4];
#pragma unroll
    for (int l = 0; l < 4; ++l) {
      int j = 4 * c + l;
      float mean = sm[j] * iv;
      float var = sq[j] * iv - mean * mean;
      float sd = sqrtf(fmaxf(var, 0.f) + 1e-5f);
      vals[0][l] = (_Float16)mean;
      vals[1][l] = has ? (_Float16)mn[j] : (_Float16)0.f;
      vals[2][l] = has ? (_Float16)mx[j] : (_Float16)0.f;
      vals[3][l] = (_Float16)sd;
    }
    int f0 = g * SEG + 4 * c;
#pragma unroll
    for (int a = 0; a < 4; ++a) {
      int kk0 = a * F + f0;
      int kt = kk0 >> 5, q = (kk0 >> 3) & 3, j0 = kk0 & 7;
      *(f16x4*)(agg + (tb + kt) * 512 + (q * 16 + m) * 8 + j0) = vals[a];
    }
  }
}

// ---------------- Phase B: global-direct MFMA GEMM + fused BN column stats ----------------
#define MFMA16(a, b, c) __builtin_amdgcn_mfma_f32_16x16x32_f16(a, b, c, 0, 0, 0)

template <int F, int FO, int FOP, bool RELU, bool STATS, typename OT>
__launch_bounds__(256)
__global__ void k_mlp(const _Float16* __restrict__ hin, const _Float16* __restrict__ agg,
                      const float* __restrict__ s1g, const float* __restrict__ s2g,
                      const _Float16* __restrict__ Wt, const float* __restrict__ bias,
                      OT* __restrict__ hout, float* __restrict__ csum,
                      float* __restrict__ csq) {
  constexpr int F32 = F / 32;
  constexpr int KTA = F / 8;
  constexpr int NT = FOP / 16;
  constexpr int PPW = (2 * NT) / 4;
  constexpr int XW = F + 8;
  __shared__ __align__(16) _Float16 s_x[32][XW];
  __shared__ float s_cs[2][FOP];

  const int tid = threadIdx.x;
  const int n0 = blockIdx.x * 32;

  for (int idx = tid; idx < 32 * (F / 8); idx += 256) {
    int r = idx / (F / 8), c = idx % (F / 8);
    *(f16x8*)&s_x[r][8 * c] = *(const f16x8*)&hin[(size_t)(n0 + r) * F + 8 * c];
  }
  if (STATS)
    for (int u = tid; u < 2 * FOP; u += 256) (&s_cs[0][0])[u] = 0.f;
  __syncthreads();

  const int w = tid >> 6, ln = tid & 63;
  const int lm = ln & 15, q = ln >> 4;
  const int mt = w & 1;
  const int arow = mt * 16 + lm;
  f32x4 acc0[PPW], acc1[PPW], acc2[PPW];
#pragma unroll
  for (int i = 0; i < PPW; ++i)
#pragma unroll
    for (int t = 0; t < 4; ++t) { acc0[i][t] = 0.f; acc1[i][t] = 0.f; acc2[i][t] = 0.f; }

#pragma unroll
  for (int kt = 0; kt < F32; ++kt) {
    f16x8 a = *(const f16x8*)&s_x[arow][kt * 32 + 8 * q];
#pragma unroll
    for (int i = 0; i < PPW; ++i) {
      int nt = (w >> 1) + 2 * i;
      f16x8 b = *(const f16x8*)&Wt[(((size_t)kt * NT + nt) * 64 + ln) * 8];
      acc0[i] = MFMA16(a, b, acc0[i]);
    }
  }
  const size_t atb = (size_t)(blockIdx.x * 2 + mt) * KTA;
#pragma unroll
  for (int kt = 0; kt < KTA; ++kt) {
    f16x8 a = *(const f16x8*)&agg[(atb + kt) * 512 + ln * 8];
#pragma unroll
    for (int i = 0; i < PPW; ++i) {
      int nt = (w >> 1) + 2 * i;
      f16x8 b0 = *(const f16x8*)&Wt[(((size_t)(F32 + kt) * NT + nt) * 64 + ln) * 8];
      acc0[i] = MFMA16(a, b0, acc0[i]);
      f16x8 b1 = *(const f16x8*)&Wt[(((size_t)(F32 + KTA + kt) * NT + nt) * 64 + ln) * 8];
      acc1[i] = MFMA16(a, b1, acc1[i]);
      f16x8 b2 = *(const f16x8*)&Wt[(((size_t)(F32 + 2 * KTA + kt) * NT + nt) * 64 + ln) * 8];
      acc2[i] = MFMA16(a, b2, acc2[i]);
    }
  }

  float s1r[4], s2r[4];
#pragma unroll
  for (int t = 0; t < 4; ++t) {
    int node = n0 + mt * 16 + q * 4 + t;
    s1r[t] = s1g[node];
    s2r[t] = s2g[node];
  }
#pragma unroll
  for (int i = 0; i < PPW; ++i) {
    int nt = (w >> 1) + 2 * i;
    int ncol = nt * 16 + lm;
    if (FOP == FO || ncol < FO) {
      float bs = bias[ncol];
      float cs = 0.f, cq = 0.f;
#pragma unroll
      for (int t = 0; t < 4; ++t) {
        int node = n0 + mt * 16 + q * 4 + t;
        float v = acc0[i][t] + s1r[t] * acc1[i][t] + s2r[t] * acc2[i][t] + bs;
        if (RELU) v = fmaxf(v, 0.f);
        hout[(size_t)node * FO + ncol] = (OT)v;
        cs += v;
        cq += v * v;
      }
      if (STATS) {
        atomicAdd(&s_cs[0][ncol], cs);
        atomicAdd(&s_cs[1][ncol], cq);
      }
    }
  }
  if (STATS) {
    __syncthreads();
    if (tid < FO) {
      atomicAdd(&csum[tid], s_cs[0][tid]);
      atomicAdd(&csq[tid], s_cs[1][tid]);
    }
  }
}

// ---------------- BN apply ----------------
__global__ void k_bn16(_Float16* __restrict__ h, const float* __restrict__ csum,
                       const float* __restrict__ csq, const float* __restrict__ gg,
                       const float* __restrict__ be, int n, int fo, int relu) {
  int i = blockIdx.x * 256 + threadIdx.x;
  int total = (n * fo) >> 3;
  if (i >= total) return;
  int c0 = (i << 3) % fo;
  float invn = 1.f / (float)n;
  f16x8 v = *(const f16x8*)&h[(size_t)i << 3];
  f16x8 o;
#pragma unroll
  for (int j = 0; j < 8; ++j) {
    int c = c0 + j;
    float mu = csum[c] * invn;
    float var = csq[c] * invn - mu * mu;
    float rs = rsqrtf(var + 1e-5f);
    float x = ((float)v[j] - mu) * rs * gg[c] + be[c];
    if (relu) x = fmaxf(x, 0.f);
    o[j] = (_Float16)x;
  }
  *(f16x8*)&h[(size_t)i << 3] = o;
}

__global__ void k_bnf(float* __restrict__ h, const float* __restrict__ csum,
                      const float* __restrict__ csq, const float* __restrict__ gg,
                      const float* __restrict__ be, int n, int fo, int relu) {
  int i = blockIdx.x * 256 + threadIdx.x;
  if (i >= n * fo) return;
  int c = i % fo;
  float invn = 1.f / (float)n;
  float mu = csum[c] * invn;
  float var = csq[c] * invn - mu * mu;
  float rs = rsqrtf(var + 1e-5f);
  float v = (h[i] - mu) * rs * gg[c] + be[c];
  if (relu) v = fmaxf(v, 0.f);
  h[i] = v;
}

// ---------------- pooling + head ----------------
__global__ void k_pool(const float* __restrict__ h, const int* __restrict__ batch,
                       float* __restrict__ zsum, float* __restrict__ gcnt, int n) {
  __shared__ float sv[NGRAPH * 20];
  __shared__ float sc[NGRAPH];
  int tid = threadIdx.x;
  for (int u = tid; u < NGRAPH * 20; u += 256) sv[u] = 0.f;
  if (tid < NGRAPH) sc[tid] = 0.f;
  __syncthreads();
  int i = blockIdx.x * 256 + tid;
  if (i < n) {
    int g = batch[i];
    atomicAdd(&sc[g], 1.f);
    for (int j = 0; j < 20; ++j) atomicAdd(&sv[g * 20 + j], h[(size_t)i * 20 + j]);
  }
  __syncthreads();
  if (tid < NGRAPH && sc[tid] != 0.f) {
    atomicAdd(&gcnt[tid], sc[tid]);
    for (int j = 0; j < 20; ++j) atomicAdd(&zsum[tid * 20 + j], sv[tid * 20 + j]);
  }
}

__global__ void k_head(const float* __restrict__ zsum, const float* __restrict__ gcnt,
                       const float* __restrict__ wl, const float* __restrict__ bl,
                       float* __restrict__ out) {
  int g = threadIdx.x;
  if (g >= NGRAPH) return;
  float z[20];
  float icg = 1.f / fmaxf(gcnt[g], 1.f);
#pragma unroll
  for (int j = 0; j < 20; ++j) {
    z[j] = zsum[g * 20 + j] * icg;
    out[NGRAPH * 11 + g * 20 + j] = z[j];  // second output: z
  }
  float lo[11];
#pragma unroll
  for (int o = 0; o < 11; ++o) {
    float a = bl[o];
    for (int j = 0; j < 20; ++j) a += z[j] * wl[j * 11 + o];
    lo[o] = a;
  }
  float m = lo[0];
  for (int o = 1; o < 11; ++o) m = fmaxf(m, lo[o]);
  float s = 0.f;
  for (int o = 0; o < 11; ++o) { lo[o] = expf(lo[o] - m); s += lo[o]; }
  float is = 1.f / s;
  for (int o = 0; o < 11; ++o) out[g * 11 + o] = lo[o] * is;  // first output: softmax
}

// ---------------- launch ----------------
static inline char* carve(char*& p, size_t bytes) {
  char* r = p;
  p += (bytes + 255) & ~(size_t)255;
  return r;
}

extern "C" void kernel_launch(void* const* d_in, const int* in_sizes, int n_in,
                              void* d_out, int out_size, void* d_ws, size_t ws_size,
                              hipStream_t stream) {
  const float* x = (const float*)d_in[0];
  const int* ei = (const int*)d_in[1];
  const int* batch = (const int*)d_in[2];
  const float* W0 = (const float*)d_in[3];
  const float* b0 = (const float*)d_in[4];
  const float* W1 = (const float*)d_in[5];
  const float* b1 = (const float*)d_in[6];
  const float* W2 = (const float*)d_in[7];
  const float* b2 = (const float*)d_in[8];
  const float* W3 = (const float*)d_in[9];
  const float* b3 = (const float*)d_in[10];
  const float* g0 = (const float*)d_in[11];
  const float* be0 = (const float*)d_in[12];
  const float* g1 = (const float*)d_in[13];
  const float* be1 = (const float*)d_in[14];
  const float* g2 = (const float*)d_in[15];
  const float* be2 = (const float*)d_in[16];
  const float* wl = (const float*)d_in[17];
  const float* bl = (const float*)d_in[18];
  float* out = (float*)d_out;

  const int E = in_sizes[1] / 2;       // 3200000
  const int NB = (NN + 255) / 256;     // 391
  const int BCAP = E / NPART + 65536;  // bucket capacity

  char* p = (char*)d_ws;
  int* cnt = (int*)carve(p, (size_t)NN * 4);
  int* row_ptr = (int*)carve(p, (size_t)(NN + 1) * 4);
  int* bsum = (int*)carve(p, 2048);
  int* boff = (int*)carve(p, 2048);
  int* bcur = (int*)carve(p, 256);
  int* colv = (int*)carve(p, (size_t)E * 4);
  unsigned long long* bkt = (unsigned long long*)carve(p, (size_t)NPART * BCAP * 8);
  int* dhist = (int*)carve(p, (size_t)NPART * DB * NPB * 4);
  float* invd = (float*)carve(p, (size_t)NN * 4);
  float* s1v = (float*)carve(p, (size_t)NN * 4);
  float* s2v = (float*)carve(p, (size_t)NN * 4);
  _Float16* Wt0 = (_Float16*)carve(p, (size_t)96 * 832 * 2);
  _Float16* Wt1 = (_Float16*)carve(p, (size_t)64 * 1248 * 2);
  _Float16* Wt2 = (_Float16*)carve(p, (size_t)32 * 832 * 2);
  _Float16* Wt3 = (_Float16*)carve(p, (size_t)32 * 416 * 2);
  float* cs = (float*)carve(p, 192 * 4);
  float* csum = cs;
  float* csq = cs + 96;
  float* pacc = (float*)carve(p, (NGRAPH * 20 + NGRAPH) * 4);
  float* zsum = pacc;
  float* gcnt = pacc + NGRAPH * 20;
  _Float16* x16 = (_Float16*)carve(p, (size_t)NN * 64 * 2);
  _Float16* hA16 = (_Float16*)carve(p, (size_t)NN * 96 * 2);
  _Float16* hB16 = (_Float16*)carve(p, (size_t)NN * 96 * 2);
  _Float16* aggb = (_Float16*)carve(p, (size_t)NN * 4 * 96 * 2);
  float* h3 = (float*)x16;  // reuse: x16 dead after L0

  // CSR: block-coop bin (512/chunk) -> LDS hist -> slice-scan -> atomic-free fill
  hipMemsetAsync(bcur, 0, 256, stream);
  hipMemsetAsync(pacc, 0, (NGRAPH * 20 + NGRAPH) * 4, stream);
  k_binstage<<<768, 256, 0, stream>>>(ei, bcur, bkt, BCAP, E);
  k_dhist<<<NPART * DB, 256, 0, stream>>>(bkt, bcur, BCAP, dhist);
  k_mergesum<<<NB, 256, 0, stream>>>(dhist, cnt, bsum, NN);
  k_scanb<<<1, 512, 0, stream>>>(bsum, boff, NB);
  k_scatter<<<NB, 256, 0, stream>>>(cnt, boff, row_ptr, NN, E);
  k_nodesc<<<NB, 256, 0, stream>>>(cnt, invd, s1v, s2v, NN);
  k_binfill<<<NPART * DB, 256, 0, stream>>>(bkt, bcur, BCAP, dhist, row_ptr, colv);

  // fp16 swizzled weights + fp16 x
  k_wtprep<<<(96 * 832 + 255) / 256, 256, 0, stream>>>(W0, Wt0, 832, 96, 96);
  k_wtprep<<<(64 * 1248 + 255) / 256, 256, 0, stream>>>(W1, Wt1, 1248, 64, 64);
  k_wtprep<<<(32 * 832 + 255) / 256, 256, 0, stream>>>(W2, Wt2, 832, 32, 32);
  k_wtprep<<<(32 * 416 + 255) / 256, 256, 0, stream>>>(W3, Wt3, 416, 20, 32);
  k_xconv<<<(NN * 64 + 255) / 256, 256, 0, stream>>>(x, x16, NN * 64);

  const int GP = NN / 32;  // 3125

  // Layer 0: (64 -> 96), BN + ReLU (stats fused in mlp)
  hipMemsetAsync(cs, 0, 192 * 4, stream);
  k_agg<64, 6><<<GP, 256, 0, stream>>>(x16, row_ptr, colv, invd, aggb);
  k_mlp<64, 96, 96, false, true, _Float16><<<GP, 256, 0, stream>>>(x16, aggb, s1v, s2v, Wt0, b0, hA16, csum, csq);
  k_bn16<<<(NN * 96 / 8 + 255) / 256, 256, 0, stream>>>(hA16, csum, csq, g0, be0, NN, 96, 1);

  // Layer 1: (96 -> 64), BN + ReLU
  hipMemsetAsync(cs, 0, 192 * 4, stream);
  k_agg<96, 4><<<GP, 256, 0, stream>>>(hA16, row_ptr, colv, invd, aggb);
  k_mlp<96, 64, 64, false, true, _Float16><<<GP, 256, 0, stream>>>(hA16, aggb, s1v, s2v, Wt1, b1, hB16, csum, csq);
  k_bn16<<<(NN * 64 / 8 + 255) / 256, 256, 0, stream>>>(hB16, csum, csq, g1, be1, NN, 64, 1);

  // Layer 2: (64 -> 32), ReLU fused, no BN
  k_agg<64, 6><<<GP, 256, 0, stream>>>(hB16, row_ptr, colv, invd, aggb);
  k_mlp<64, 32, 32, true, false, _Float16><<<GP, 256, 0, stream>>>(hB16, aggb, s1v, s2v, Wt2, b2, hA16, csum, csq);

  // Layer 3: (32 -> 20), BN (no ReLU), fp32 out
  hipMemsetAsync(cs, 0, 192 * 4, stream);
  k_agg<32, 8><<<GP, 256, 0, stream>>>(hA16, row_ptr, colv, invd, aggb);
  k_mlp<32, 20, 32, false, true, float><<<GP, 256, 0, stream>>>(hA16, aggb, s1v, s2v, Wt3, b3, h3, csum, csq);
  k_bnf<<<(NN * 20 + 255) / 256, 256, 0, stream>>>(h3, csum, csq, g2, be2, NN, 20, 0);

  // global mean pool + linear + softmax
  k_pool<<<NB, 256, 0, stream>>>(h3, batch, zsum, gcnt, NN);
  k_head<<<1, 64, 0, stream>>>(zsum, gcnt, wl, bl, out);
}